// Round 6
// baseline (935.804 us; speedup 1.0000x reference)
//
#include <hip/hip_runtime.h>
#include <hip/hip_bf16.h>

#define NN 100000
#define NE 3200000
#define NG 1000
#define BN_EPS 1e-5f

#define BKT_SH 6            // 64 nodes per bucket
#define BKTN 64
#define NBKT 1563           // ceil(NN/64)
#define CHUNK 8192          // edges per bin_kernel block
#define NBINBLK 391         // ceil(NE/CHUNK)

typedef __attribute__((ext_vector_type(8))) short short8v;
typedef __attribute__((ext_vector_type(4))) float f32x4;

__device__ __forceinline__ unsigned int f2bf(float f) {
    unsigned int u = __builtin_bit_cast(unsigned int, f);
    u += 0x7FFFu + ((u >> 16) & 1u);        // round-to-nearest-even
    return u >> 16;
}
__device__ __forceinline__ float bf2f(unsigned int h16) {
    return __builtin_bit_cast(float, h16 << 16);
}

// ---------------- bucket histogram ----------------
__global__ __launch_bounds__(256) void bucket_count_kernel(const int* __restrict__ dst,
                                                           int* __restrict__ bcnt) {
    __shared__ int h[NBKT];
    int t = threadIdx.x;
    for (int i = t; i < NBKT; i += 256) h[i] = 0;
    __syncthreads();
    int gid = blockIdx.x * 256 + t;
    for (int e = gid; e < NE; e += NBINBLK * 256) atomicAdd(&h[dst[e] >> BKT_SH], 1);
    __syncthreads();
    for (int i = t; i < NBKT; i += 256) if (h[i]) atomicAdd(&bcnt[i], h[i]);
}

// ---------------- exclusive scan of bucket counts ----------------
__global__ void bucket_scan_kernel(const int* __restrict__ bcnt, int* __restrict__ bbase,
                                   int* __restrict__ bcur) {
    __shared__ int wsum[16];
    __shared__ int lcarry;
    int t = threadIdx.x, lane = t & 63, w = t >> 6;
    if (t == 0) lcarry = 0;
    __syncthreads();
    for (int base = 0; base < NBKT; base += 1024) {
        int i = base + t;
        int v = (i < NBKT) ? bcnt[i] : 0;
        int incl = v;
        #pragma unroll
        for (int d = 1; d < 64; d <<= 1) { int u = __shfl_up(incl, d, 64); if (lane >= d) incl += u; }
        if (lane == 63) wsum[w] = incl;
        __syncthreads();
        if (w == 0) {
            int s = (lane < 16) ? wsum[lane] : 0;
            #pragma unroll
            for (int d = 1; d < 16; d <<= 1) { int u = __shfl_up(s, d, 64); if (lane >= d) s += u; }
            if (lane < 16) wsum[lane] = s;
        }
        __syncthreads();
        int excl = lcarry + (w ? wsum[w - 1] : 0) + incl - v;
        if (i < NBKT) { bbase[i] = excl; bcur[i] = excl; }
        __syncthreads();
        if (t == 0) lcarry += wsum[15];
        __syncthreads();
    }
}

// ---------------- binning: group edges by 64-node bucket ----------------
__global__ __launch_bounds__(256) void bin_kernel(const int* __restrict__ src,
        const int* __restrict__ dst, int* __restrict__ bcur,
        unsigned int* __restrict__ ebin) {
    __shared__ unsigned int ebuf[CHUNK];        // 32 KB
    __shared__ unsigned short bids[CHUNK];      // 16 KB
    __shared__ int hist[NBKT], lbase[NBKT], lcur[NBKT], delta[NBKT];   // 25 KB
    __shared__ int wsum4[4];
    __shared__ int carry;
    int t = threadIdx.x;
    int lane = t & 63, w = t >> 6;
    int c0 = blockIdx.x * CHUNK;
    int cnt = min(CHUNK, NE - c0);
    for (int i = t; i < NBKT; i += 256) hist[i] = 0;
    if (t == 0) carry = 0;
    __syncthreads();
    for (int i = t; i < cnt; i += 256) atomicAdd(&hist[dst[c0 + i] >> BKT_SH], 1);
    __syncthreads();
    for (int bb = 0; bb < NBKT; bb += 256) {
        int i = bb + t;
        int v = (i < NBKT) ? hist[i] : 0;
        int incl = v;
        #pragma unroll
        for (int d2 = 1; d2 < 64; d2 <<= 1) { int u = __shfl_up(incl, d2, 64); if (lane >= d2) incl += u; }
        if (lane == 63) wsum4[w] = incl;
        __syncthreads();
        int wo = 0;
        if (w > 0) wo = wsum4[0];
        if (w > 1) wo += wsum4[1];
        if (w > 2) wo += wsum4[2];
        int excl = carry + wo + incl - v;
        if (i < NBKT) { lbase[i] = excl; lcur[i] = excl; }
        int tot = wsum4[0] + wsum4[1] + wsum4[2] + wsum4[3];
        __syncthreads();
        if (t == 0) carry += tot;
        __syncthreads();
    }
    for (int b = t; b < NBKT; b += 256) {
        int hh = hist[b];
        delta[b] = (hh ? atomicAdd(&bcur[b], hh) : 0) - lbase[b];
    }
    __syncthreads();
    for (int i = t; i < cnt; i += 256) {
        int d = dst[c0 + i];
        int s = src[c0 + i];
        int b = d >> BKT_SH;
        unsigned int entry = ((unsigned int)s << BKT_SH) | (unsigned int)(d & (BKTN - 1));
        int p = atomicAdd(&lcur[b], 1);
        ebuf[p] = entry;
        bids[p] = (unsigned short)b;
    }
    __syncthreads();
    for (int i = t; i < cnt; i += 256) {
        ebin[delta[bids[i]] + i] = ebuf[i];
    }
}

// ---------------- per-bucket counting sort -> per-node CSR ----------------
__global__ __launch_bounds__(256) void sort_kernel(const unsigned int* __restrict__ ebin,
        const int* __restrict__ bbase, const int* __restrict__ bcnt,
        int* __restrict__ noffs, int* __restrict__ csrc) {
    __shared__ int nh[BKTN], ncur[BKTN];
    int b = blockIdx.x, t = threadIdx.x;
    int base = bbase[b], cnt = bcnt[b];
    if (t < BKTN) nh[t] = 0;
    __syncthreads();
    for (int i = t; i < cnt; i += 256) atomicAdd(&nh[ebin[base + i] & (BKTN - 1)], 1);
    __syncthreads();
    if (t < 64) {
        int v = nh[t], incl = v;
        #pragma unroll
        for (int d = 1; d < 64; d <<= 1) { int u = __shfl_up(incl, d, 64); if (t >= d) incl += u; }
        int excl = incl - v;
        ncur[t] = excl;
        int node = (b << BKT_SH) + t;
        if (node < NN) noffs[node] = base + excl;
    }
    if (b == 0 && t == 0) noffs[NN] = NE;
    __syncthreads();
    for (int i = t; i < cnt; i += 256) {
        unsigned int e = ebin[base + i];
        int p = atomicAdd(&ncur[e & (BKTN - 1)], 1);
        csrc[base + p] = (int)(e >> BKT_SH);
    }
}

// ---------------- pack x f32 -> u32 (bf16 pair: channels 2l, 2l+1) ----------------
__global__ void pack_x_kernel(const float* __restrict__ x, unsigned int* __restrict__ xp) {
    int tid = blockIdx.x * 256 + threadIdx.x;   // NN*64 exact
    float2 v = ((const float2*)x)[tid];
    xp[tid] = f2bf(v.x) | (f2bf(v.y) << 16);
}

// ---------------- weight prep: Wt[c][k] bf16-packed = W[k][c] ----------------
__global__ void wprep_kernel(const float* __restrict__ W1a, const float* __restrict__ W1b,
                             const float* __restrict__ W2a, const float* __restrict__ W2b,
                             unsigned int* __restrict__ Wt) {
    int tid = blockIdx.x * 256 + threadIdx.x;   // 4*128*64 = 32768
    int m = tid >> 13;
    int r = tid & 8191;
    int c = r >> 6, kh = r & 63;
    const float* W = (m == 0) ? W1a : (m == 1) ? W1b : (m == 2) ? W2a : W2b;
    float a = W[(2 * kh) * 128 + c];
    float b = W[(2 * kh + 1) * 128 + c];
    Wt[tid] = f2bf(a) | (f2bf(b) << 16);
}

// ---------------- aggregation: one wave per node, ILP-8, packed bf16 in/out ----------------
__global__ __launch_bounds__(256) void aggregate_gather_kernel(
        const unsigned int* __restrict__ xp, const int* __restrict__ noffs,
        const int* __restrict__ csrc, unsigned int* __restrict__ outp) {
    int node = __builtin_amdgcn_readfirstlane(blockIdx.x * 4 + (threadIdx.x >> 6));
    int lane = threadIdx.x & 63;
    unsigned int u = xp[(size_t)node * 64 + lane];
    float alo = bf2f(u & 0xFFFFu), ahi = bf2f(u >> 16);
    int s = noffs[node], e = noffs[node + 1];
    int i = s;
    for (; i + 8 <= e; i += 8) {
        int i0 = csrc[i + 0], i1 = csrc[i + 1], i2 = csrc[i + 2], i3 = csrc[i + 3];
        int i4 = csrc[i + 4], i5 = csrc[i + 5], i6 = csrc[i + 6], i7 = csrc[i + 7];
        unsigned int u0 = xp[(size_t)i0 * 64 + lane];
        unsigned int u1 = xp[(size_t)i1 * 64 + lane];
        unsigned int u2 = xp[(size_t)i2 * 64 + lane];
        unsigned int u3 = xp[(size_t)i3 * 64 + lane];
        unsigned int u4 = xp[(size_t)i4 * 64 + lane];
        unsigned int u5 = xp[(size_t)i5 * 64 + lane];
        unsigned int u6 = xp[(size_t)i6 * 64 + lane];
        unsigned int u7 = xp[(size_t)i7 * 64 + lane];
        alo += bf2f(u0 & 0xFFFFu); ahi += bf2f(u0 >> 16);
        alo += bf2f(u1 & 0xFFFFu); ahi += bf2f(u1 >> 16);
        alo += bf2f(u2 & 0xFFFFu); ahi += bf2f(u2 >> 16);
        alo += bf2f(u3 & 0xFFFFu); ahi += bf2f(u3 >> 16);
        alo += bf2f(u4 & 0xFFFFu); ahi += bf2f(u4 >> 16);
        alo += bf2f(u5 & 0xFFFFu); ahi += bf2f(u5 >> 16);
        alo += bf2f(u6 & 0xFFFFu); ahi += bf2f(u6 >> 16);
        alo += bf2f(u7 & 0xFFFFu); ahi += bf2f(u7 >> 16);
    }
    for (; i < e; ++i) {
        int sv = csrc[i];
        unsigned int uu = xp[(size_t)sv * 64 + lane];
        alo += bf2f(uu & 0xFFFFu); ahi += bf2f(uu >> 16);
    }
    outp[(size_t)node * 64 + lane] = f2bf(alo) | (f2bf(ahi) << 16);
}

// ---------------- fused MLP: H2 = (relu(H0@Wa + ba))@Wb + bb, all bf16 MFMA ----------------
// In: packed rows [NN][64]u32. WtA/WtB: [128][64]u32 = Wᵀ bf16. Out: packed [NN][64]u32.
__global__ __launch_bounds__(256) void mlp_kernel(const unsigned int* __restrict__ Pin,
        const unsigned int* __restrict__ WtA, const float* __restrict__ bA,
        const unsigned int* __restrict__ WtB, const float* __restrict__ bB,
        unsigned int* __restrict__ Pout) {
    __shared__ unsigned int tile[64 * 68];      // rows padded to 68 u32 (272 B)
    int t = threadIdx.x, l = t & 63, w = t >> 6;
    int node0 = blockIdx.x * 64;
    int rbase = w * 16;
    int g = l >> 4, r = l & 15;
    int g4 = g * 4;

    // stage this wave's 16 rows (coalesced 16B loads, 2-way LDS aliasing only)
    const uint4* P4 = (const uint4*)Pin;
    #pragma unroll
    for (int i = 0; i < 4; ++i) {
        int rl = rbase + i * 4 + g;
        int node = node0 + rl;
        uint4 v = make_uint4(0u, 0u, 0u, 0u);
        if (node < NN) v = P4[(size_t)node * 16 + r];
        *(uint4*)&tile[rl * 68 + r * 4] = v;
    }
    // no barrier: each wave reads only its own rows

    // GEMM1 (swapped): D = WtAᵀ-block × H0ᵀ → lane holds rows r, cols cb*16+g4+reg
    f32x4 acc1[8];
    #pragma unroll
    for (int cb = 0; cb < 8; ++cb) acc1[cb] = (f32x4){0.f, 0.f, 0.f, 0.f};
    #pragma unroll
    for (int kk = 0; kk < 4; ++kk) {
        short8v a = *(short8v*)&tile[(rbase + r) * 68 + kk * 16 + g4];
        #pragma unroll
        for (int cb = 0; cb < 8; ++cb) {
            short8v wv = *(const short8v*)&WtA[(size_t)(cb * 16 + r) * 64 + kk * 16 + g4];
            acc1[cb] = __builtin_amdgcn_mfma_f32_16x16x32_bf16(wv, a, acc1[cb], 0, 0, 0);
        }
    }
    // epilogue 1: bias + relu + bf16 pack -> back into own tile rows
    #pragma unroll
    for (int cb = 0; cb < 8; ++cb) {
        int c0 = cb * 16 + g4;
        float4 bi = *(const float4*)&bA[c0];
        float h0 = fmaxf(acc1[cb][0] + bi.x, 0.f);
        float h1 = fmaxf(acc1[cb][1] + bi.y, 0.f);
        float h2 = fmaxf(acc1[cb][2] + bi.z, 0.f);
        float h3 = fmaxf(acc1[cb][3] + bi.w, 0.f);
        uint2 pk;
        pk.x = f2bf(h0) | (f2bf(h1) << 16);
        pk.y = f2bf(h2) | (f2bf(h3) << 16);
        *(uint2*)&tile[(rbase + r) * 68 + (c0 >> 1)] = pk;
    }
    // GEMM2
    f32x4 acc2[8];
    #pragma unroll
    for (int cb = 0; cb < 8; ++cb) acc2[cb] = (f32x4){0.f, 0.f, 0.f, 0.f};
    #pragma unroll
    for (int kk = 0; kk < 4; ++kk) {
        short8v a = *(short8v*)&tile[(rbase + r) * 68 + kk * 16 + g4];
        #pragma unroll
        for (int cb = 0; cb < 8; ++cb) {
            short8v wv = *(const short8v*)&WtB[(size_t)(cb * 16 + r) * 64 + kk * 16 + g4];
            acc2[cb] = __builtin_amdgcn_mfma_f32_16x16x32_bf16(wv, a, acc2[cb], 0, 0, 0);
        }
    }
    // epilogue 2: bias + bf16 pack -> global
    int node = node0 + rbase + r;
    if (node < NN) {
        #pragma unroll
        for (int cb = 0; cb < 8; ++cb) {
            int c0 = cb * 16 + g4;
            float4 bi = *(const float4*)&bB[c0];
            float h0 = acc2[cb][0] + bi.x;
            float h1 = acc2[cb][1] + bi.y;
            float h2 = acc2[cb][2] + bi.z;
            float h3 = acc2[cb][3] + bi.w;
            uint2 pk;
            pk.x = f2bf(h0) | (f2bf(h1) << 16);
            pk.y = f2bf(h2) | (f2bf(h3) << 16);
            *(uint2*)&Pout[(size_t)node * 64 + (c0 >> 1)] = pk;
        }
    }
}

// ---------------- BN stats over packed rows ----------------
__global__ void bn_stats_kernel(const unsigned int* __restrict__ P, float* __restrict__ stats) {
    int tid = blockIdx.x * 256 + threadIdx.x;
    int c0 = 2 * (tid & 63);
    float s0 = 0.f, s1 = 0.f, q0 = 0.f, q1 = 0.f;
    const int total = NN * 64;
    for (int i = tid; i < total; i += 1024 * 256) {
        unsigned int u = P[i];
        float a = bf2f(u & 0xFFFFu), b = bf2f(u >> 16);
        s0 += a; q0 += a * a; s1 += b; q1 += b * b;
    }
    atomicAdd(&stats[c0], s0);
    atomicAdd(&stats[c0 + 1], s1);
    atomicAdd(&stats[128 + c0], q0);
    atomicAdd(&stats[128 + c0 + 1], q1);
}

// ---------------- BN + ReLU + repack ----------------
__global__ void bn_relu_pack_kernel(const unsigned int* __restrict__ Pin,
        const float* __restrict__ stats, const float* __restrict__ gamma,
        const float* __restrict__ beta, unsigned int* __restrict__ Pout) {
    int tid = blockIdx.x * 256 + threadIdx.x;   // NN*64 exact
    int l = tid & 63;
    int c0 = 2 * l;
    const float inv = 1.0f / NN;
    unsigned int u = Pin[tid];
    float u0 = bf2f(u & 0xFFFFu), u1 = bf2f(u >> 16);
    float m0 = stats[c0] * inv;
    float v0 = stats[128 + c0] * inv - m0 * m0;
    float m1 = stats[c0 + 1] * inv;
    float v1 = stats[128 + c0 + 1] * inv - m1 * m1;
    float o0 = fmaxf((u0 - m0) * rsqrtf(v0 + BN_EPS) * gamma[c0] + beta[c0], 0.f);
    float o1 = fmaxf((u1 - m1) * rsqrtf(v1 + BN_EPS) * gamma[c0 + 1] + beta[c0 + 1], 0.f);
    Pout[tid] = f2bf(o0) | (f2bf(o1) << 16);
}

// ---------------- pooling over packed rows ----------------
__global__ void pool_kernel(const unsigned int* __restrict__ hb,
                            const int* __restrict__ batch, float* __restrict__ pooled) {
    int g = blockIdx.x;
    int l = threadIdx.x;   // 64
    int a = 0, b = NN;
    while (a < b) { int m = (a + b) >> 1; if (batch[m] < g) a = m + 1; else b = m; }
    int start = a;
    b = NN;
    while (a < b) { int m = (a + b) >> 1; if (batch[m] < g + 1) a = m + 1; else b = m; }
    int end = a;
    float s0 = 0.f, s1 = 0.f;
    for (int i = start; i < end; ++i) {
        unsigned int u = hb[(size_t)i * 64 + l];
        s0 += bf2f(u & 0xFFFFu);
        s1 += bf2f(u >> 16);
    }
    ((float2*)pooled)[g * 64 + l] = make_float2(s0, s1);
}

// ---------------- head: logits + log_softmax ----------------
__global__ void head_kernel(const float* __restrict__ pooled, const float* __restrict__ Wlin,
                            const float* __restrict__ blin, float* __restrict__ out) {
    int g = blockIdx.x;
    int lane = threadIdx.x;  // 64
    float2 p = ((const float2*)pooled)[g * 64 + lane];
    float l[10];
    #pragma unroll
    for (int o = 0; o < 10; ++o) {
        float partial = p.x * Wlin[(2 * lane) * 10 + o] + p.y * Wlin[(2 * lane + 1) * 10 + o];
        #pragma unroll
        for (int m = 1; m < 64; m <<= 1) partial += __shfl_xor(partial, m, 64);
        l[o] = partial + blin[o];
    }
    float mx = l[0];
    #pragma unroll
    for (int o = 1; o < 10; ++o) mx = fmaxf(mx, l[o]);
    float se = 0.f;
    #pragma unroll
    for (int o = 0; o < 10; ++o) se += expf(l[o] - mx);
    float lse = mx + logf(se);
    if (lane == 0) {
        #pragma unroll
        for (int o = 0; o < 10; ++o) out[g * 10 + o] = l[o] - lse;
    }
}

extern "C" void kernel_launch(void* const* d_in, const int* in_sizes, int n_in,
                              void* d_out, int out_size, void* d_ws, size_t ws_size,
                              hipStream_t stream) {
    const float* x    = (const float*)d_in[0];
    const int*   edge = (const int*)d_in[1];   // [2][NE]
    const int*   batch= (const int*)d_in[2];
    const float* W1a  = (const float*)d_in[3];
    const float* b1a  = (const float*)d_in[4];
    const float* W1b  = (const float*)d_in[5];
    const float* b1b  = (const float*)d_in[6];
    const float* g1   = (const float*)d_in[7];
    const float* be1  = (const float*)d_in[8];
    const float* W2a  = (const float*)d_in[9];
    const float* b2a  = (const float*)d_in[10];
    const float* W2b  = (const float*)d_in[11];
    const float* b2b  = (const float*)d_in[12];
    const float* g2   = (const float*)d_in[13];
    const float* be2  = (const float*)d_in[14];
    const float* Wlin = (const float*)d_in[15];
    const float* blin = (const float*)d_in[16];
    float* out = (float*)d_out;

    char* ws = (char*)d_ws;
    size_t off = 0;
    auto alloc = [&](size_t bytes) -> void* {
        void* p = ws + off; off += (bytes + 255) & ~(size_t)255; return p;
    };
    unsigned int* Pa   = (unsigned int*)alloc((size_t)NN * 64 * 4);
    unsigned int* Pb   = (unsigned int*)alloc((size_t)NN * 64 * 4);
    unsigned int* ebin = (unsigned int*)alloc((size_t)NE * 4);
    int*   csrc   = (int*)alloc((size_t)NE * 4);
    int*   noffs  = (int*)alloc((NN + 1) * 4);
    int*   bcnt   = (int*)alloc(NBKT * 4);
    int*   bbase  = (int*)alloc(NBKT * 4);
    int*   bcur   = (int*)alloc(NBKT * 4);
    float* stats1 = (float*)alloc(256 * 4);
    float* stats2 = (float*)alloc(256 * 4);
    float* pooled = (float*)alloc(NG * 128 * 4);
    unsigned int* Wt = (unsigned int*)alloc(4 * 8192 * 4);
    unsigned int* Wt1a = Wt;
    unsigned int* Wt1b = Wt + 8192;
    unsigned int* Wt2a = Wt + 16384;
    unsigned int* Wt2b = Wt + 24576;

    const int* srcI = edge;
    const int* dstI = edge + NE;

    hipMemsetAsync(bcnt, 0, NBKT * 4, stream);
    hipMemsetAsync(stats1, 0, 256 * 4, stream);
    hipMemsetAsync(stats2, 0, 256 * 4, stream);

    bucket_count_kernel<<<NBINBLK, 256, 0, stream>>>(dstI, bcnt);
    bucket_scan_kernel<<<1, 1024, 0, stream>>>(bcnt, bbase, bcur);
    bin_kernel<<<NBINBLK, 256, 0, stream>>>(srcI, dstI, bcur, ebin);
    sort_kernel<<<NBKT, 256, 0, stream>>>(ebin, bbase, bcnt, noffs, csrc);
    wprep_kernel<<<128, 256, 0, stream>>>(W1a, W1b, W2a, W2b, Wt);
    pack_x_kernel<<<25000, 256, 0, stream>>>(x, Pa);

    // ---- layer 1 ----
    aggregate_gather_kernel<<<25000, 256, 0, stream>>>(Pa, noffs, csrc, Pb);
    mlp_kernel<<<1563, 256, 0, stream>>>(Pb, Wt1a, b1a, Wt1b, b1b, Pa);
    bn_stats_kernel<<<1024, 256, 0, stream>>>(Pa, stats1);
    bn_relu_pack_kernel<<<25000, 256, 0, stream>>>(Pa, stats1, g1, be1, Pb);
    // ---- layer 2 ----
    aggregate_gather_kernel<<<25000, 256, 0, stream>>>(Pb, noffs, csrc, Pa);
    mlp_kernel<<<1563, 256, 0, stream>>>(Pa, Wt2a, b2a, Wt2b, b2b, Pb);
    bn_stats_kernel<<<1024, 256, 0, stream>>>(Pb, stats2);
    bn_relu_pack_kernel<<<25000, 256, 0, stream>>>(Pb, stats2, g2, be2, Pa);

    pool_kernel<<<NG, 64, 0, stream>>>(Pa, batch, pooled);
    head_kernel<<<NG, 64, 0, stream>>>(pooled, Wlin, blin, out);
}

// Round 7
// 578.207 us; speedup vs baseline: 1.6185x; 1.6185x over previous
//
#include <hip/hip_runtime.h>
#include <hip/hip_bf16.h>

#define NN 100000
#define NE 3200000
#define NG 1000
#define BN_EPS 1e-5f

#define BKT_SH 6            // 64 nodes per bucket
#define BKTN 64
#define NBKT 1563           // ceil(NN/64)
#define CHUNK 8192          // edges per bin_kernel block
#define NBINBLK 391         // ceil(NE/CHUNK)
#define BNBLK 512           // bn partial blocks

typedef __attribute__((ext_vector_type(8))) short short8v;
typedef __attribute__((ext_vector_type(4))) float f32x4;

__device__ __forceinline__ unsigned int f2bf(float f) {
    unsigned int u = __builtin_bit_cast(unsigned int, f);
    u += 0x7FFFu + ((u >> 16) & 1u);        // round-to-nearest-even
    return u >> 16;
}
__device__ __forceinline__ float bf2f(unsigned int h16) {
    return __builtin_bit_cast(float, h16 << 16);
}

// ---------------- bucket histogram ----------------
__global__ __launch_bounds__(256) void bucket_count_kernel(const int* __restrict__ dst,
                                                           int* __restrict__ bcnt) {
    __shared__ int h[NBKT];
    int t = threadIdx.x;
    for (int i = t; i < NBKT; i += 256) h[i] = 0;
    __syncthreads();
    int gid = blockIdx.x * 256 + t;
    for (int e = gid; e < NE; e += NBINBLK * 256) atomicAdd(&h[dst[e] >> BKT_SH], 1);
    __syncthreads();
    for (int i = t; i < NBKT; i += 256) if (h[i]) atomicAdd(&bcnt[i], h[i]);
}

// ---------------- exclusive scan of bucket counts ----------------
__global__ void bucket_scan_kernel(const int* __restrict__ bcnt, int* __restrict__ bbase,
                                   int* __restrict__ bcur) {
    __shared__ int wsum[16];
    __shared__ int lcarry;
    int t = threadIdx.x, lane = t & 63, w = t >> 6;
    if (t == 0) lcarry = 0;
    __syncthreads();
    for (int base = 0; base < NBKT; base += 1024) {
        int i = base + t;
        int v = (i < NBKT) ? bcnt[i] : 0;
        int incl = v;
        #pragma unroll
        for (int d = 1; d < 64; d <<= 1) { int u = __shfl_up(incl, d, 64); if (lane >= d) incl += u; }
        if (lane == 63) wsum[w] = incl;
        __syncthreads();
        if (w == 0) {
            int s = (lane < 16) ? wsum[lane] : 0;
            #pragma unroll
            for (int d = 1; d < 16; d <<= 1) { int u = __shfl_up(s, d, 64); if (lane >= d) s += u; }
            if (lane < 16) wsum[lane] = s;
        }
        __syncthreads();
        int excl = lcarry + (w ? wsum[w - 1] : 0) + incl - v;
        if (i < NBKT) { bbase[i] = excl; bcur[i] = excl; }
        __syncthreads();
        if (t == 0) lcarry += wsum[15];
        __syncthreads();
    }
}

// ---------------- binning: group edges by 64-node bucket ----------------
__global__ __launch_bounds__(256) void bin_kernel(const int* __restrict__ src,
        const int* __restrict__ dst, int* __restrict__ bcur,
        unsigned int* __restrict__ ebin) {
    __shared__ unsigned int ebuf[CHUNK];        // 32 KB
    __shared__ unsigned short bids[CHUNK];      // 16 KB
    __shared__ int hist[NBKT], lbase[NBKT], lcur[NBKT], delta[NBKT];   // 25 KB
    __shared__ int wsum4[4];
    __shared__ int carry;
    int t = threadIdx.x;
    int lane = t & 63, w = t >> 6;
    int c0 = blockIdx.x * CHUNK;
    int cnt = min(CHUNK, NE - c0);
    for (int i = t; i < NBKT; i += 256) hist[i] = 0;
    if (t == 0) carry = 0;
    __syncthreads();
    for (int i = t; i < cnt; i += 256) atomicAdd(&hist[dst[c0 + i] >> BKT_SH], 1);
    __syncthreads();
    for (int bb = 0; bb < NBKT; bb += 256) {
        int i = bb + t;
        int v = (i < NBKT) ? hist[i] : 0;
        int incl = v;
        #pragma unroll
        for (int d2 = 1; d2 < 64; d2 <<= 1) { int u = __shfl_up(incl, d2, 64); if (lane >= d2) incl += u; }
        if (lane == 63) wsum4[w] = incl;
        __syncthreads();
        int wo = 0;
        if (w > 0) wo = wsum4[0];
        if (w > 1) wo += wsum4[1];
        if (w > 2) wo += wsum4[2];
        int excl = carry + wo + incl - v;
        if (i < NBKT) { lbase[i] = excl; lcur[i] = excl; }
        int tot = wsum4[0] + wsum4[1] + wsum4[2] + wsum4[3];
        __syncthreads();
        if (t == 0) carry += tot;
        __syncthreads();
    }
    for (int b = t; b < NBKT; b += 256) {
        int hh = hist[b];
        delta[b] = (hh ? atomicAdd(&bcur[b], hh) : 0) - lbase[b];
    }
    __syncthreads();
    for (int i = t; i < cnt; i += 256) {
        int d = dst[c0 + i];
        int s = src[c0 + i];
        int b = d >> BKT_SH;
        unsigned int entry = ((unsigned int)s << BKT_SH) | (unsigned int)(d & (BKTN - 1));
        int p = atomicAdd(&lcur[b], 1);
        ebuf[p] = entry;
        bids[p] = (unsigned short)b;
    }
    __syncthreads();
    for (int i = t; i < cnt; i += 256) {
        ebin[delta[bids[i]] + i] = ebuf[i];
    }
}

// ---------------- per-bucket counting sort -> per-node CSR ----------------
__global__ __launch_bounds__(256) void sort_kernel(const unsigned int* __restrict__ ebin,
        const int* __restrict__ bbase, const int* __restrict__ bcnt,
        int* __restrict__ noffs, int* __restrict__ csrc) {
    __shared__ int nh[BKTN], ncur[BKTN];
    int b = blockIdx.x, t = threadIdx.x;
    int base = bbase[b], cnt = bcnt[b];
    if (t < BKTN) nh[t] = 0;
    __syncthreads();
    for (int i = t; i < cnt; i += 256) atomicAdd(&nh[ebin[base + i] & (BKTN - 1)], 1);
    __syncthreads();
    if (t < 64) {
        int v = nh[t], incl = v;
        #pragma unroll
        for (int d = 1; d < 64; d <<= 1) { int u = __shfl_up(incl, d, 64); if (t >= d) incl += u; }
        int excl = incl - v;
        ncur[t] = excl;
        int node = (b << BKT_SH) + t;
        if (node < NN) noffs[node] = base + excl;
    }
    if (b == 0 && t == 0) noffs[NN] = NE;
    __syncthreads();
    for (int i = t; i < cnt; i += 256) {
        unsigned int e = ebin[base + i];
        int p = atomicAdd(&ncur[e & (BKTN - 1)], 1);
        csrc[base + p] = (int)(e >> BKT_SH);
    }
}

// ---------------- pack x f32 -> u32 (bf16 pair: channels 2l, 2l+1) ----------------
__global__ void pack_x_kernel(const float* __restrict__ x, unsigned int* __restrict__ xp) {
    int tid = blockIdx.x * 256 + threadIdx.x;   // NN*64 exact
    float2 v = ((const float2*)x)[tid];
    xp[tid] = f2bf(v.x) | (f2bf(v.y) << 16);
}

// ---------------- weight prep: Wt[c][k] bf16-packed = W[k][c] ----------------
__global__ void wprep_kernel(const float* __restrict__ W1a, const float* __restrict__ W1b,
                             const float* __restrict__ W2a, const float* __restrict__ W2b,
                             unsigned int* __restrict__ Wt) {
    int tid = blockIdx.x * 256 + threadIdx.x;   // 4*128*64 = 32768
    int m = tid >> 13;
    int r = tid & 8191;
    int c = r >> 6, kh = r & 63;
    const float* W = (m == 0) ? W1a : (m == 1) ? W1b : (m == 2) ? W2a : W2b;
    float a = W[(2 * kh) * 128 + c];
    float b = W[(2 * kh + 1) * 128 + c];
    Wt[tid] = f2bf(a) | (f2bf(b) << 16);
}

// ---------------- aggregation: one wave per node, ILP-8, packed bf16 in/out ----------------
__global__ __launch_bounds__(256) void aggregate_gather_kernel(
        const unsigned int* __restrict__ xp, const int* __restrict__ noffs,
        const int* __restrict__ csrc, unsigned int* __restrict__ outp) {
    int node = __builtin_amdgcn_readfirstlane(blockIdx.x * 4 + (threadIdx.x >> 6));
    int lane = threadIdx.x & 63;
    unsigned int u = xp[(size_t)node * 64 + lane];
    float alo = bf2f(u & 0xFFFFu), ahi = bf2f(u >> 16);
    int s = noffs[node], e = noffs[node + 1];
    int i = s;
    for (; i + 8 <= e; i += 8) {
        int i0 = csrc[i + 0], i1 = csrc[i + 1], i2 = csrc[i + 2], i3 = csrc[i + 3];
        int i4 = csrc[i + 4], i5 = csrc[i + 5], i6 = csrc[i + 6], i7 = csrc[i + 7];
        unsigned int u0 = xp[(size_t)i0 * 64 + lane];
        unsigned int u1 = xp[(size_t)i1 * 64 + lane];
        unsigned int u2 = xp[(size_t)i2 * 64 + lane];
        unsigned int u3 = xp[(size_t)i3 * 64 + lane];
        unsigned int u4 = xp[(size_t)i4 * 64 + lane];
        unsigned int u5 = xp[(size_t)i5 * 64 + lane];
        unsigned int u6 = xp[(size_t)i6 * 64 + lane];
        unsigned int u7 = xp[(size_t)i7 * 64 + lane];
        alo += bf2f(u0 & 0xFFFFu); ahi += bf2f(u0 >> 16);
        alo += bf2f(u1 & 0xFFFFu); ahi += bf2f(u1 >> 16);
        alo += bf2f(u2 & 0xFFFFu); ahi += bf2f(u2 >> 16);
        alo += bf2f(u3 & 0xFFFFu); ahi += bf2f(u3 >> 16);
        alo += bf2f(u4 & 0xFFFFu); ahi += bf2f(u4 >> 16);
        alo += bf2f(u5 & 0xFFFFu); ahi += bf2f(u5 >> 16);
        alo += bf2f(u6 & 0xFFFFu); ahi += bf2f(u6 >> 16);
        alo += bf2f(u7 & 0xFFFFu); ahi += bf2f(u7 >> 16);
    }
    for (; i < e; ++i) {
        int sv = csrc[i];
        unsigned int uu = xp[(size_t)sv * 64 + lane];
        alo += bf2f(uu & 0xFFFFu); ahi += bf2f(uu >> 16);
    }
    outp[(size_t)node * 64 + lane] = f2bf(alo) | (f2bf(ahi) << 16);
}

// ---------------- fused MLP: H2 = (relu(H0@Wa + ba))@Wb + bb, all bf16 MFMA ----------------
__global__ __launch_bounds__(256) void mlp_kernel(const unsigned int* __restrict__ Pin,
        const unsigned int* __restrict__ WtA, const float* __restrict__ bA,
        const unsigned int* __restrict__ WtB, const float* __restrict__ bB,
        unsigned int* __restrict__ Pout) {
    __shared__ unsigned int tile[64 * 68];      // rows padded to 68 u32 (272 B)
    int t = threadIdx.x, l = t & 63, w = t >> 6;
    int node0 = blockIdx.x * 64;
    int rbase = w * 16;
    int g = l >> 4, r = l & 15;
    int g4 = g * 4;

    const uint4* P4 = (const uint4*)Pin;
    #pragma unroll
    for (int i = 0; i < 4; ++i) {
        int rl = rbase + i * 4 + g;
        int node = node0 + rl;
        uint4 v = make_uint4(0u, 0u, 0u, 0u);
        if (node < NN) v = P4[(size_t)node * 16 + r];
        *(uint4*)&tile[rl * 68 + r * 4] = v;
    }
    // no barrier: each wave reads only its own rows

    f32x4 acc1[8];
    #pragma unroll
    for (int cb = 0; cb < 8; ++cb) acc1[cb] = (f32x4){0.f, 0.f, 0.f, 0.f};
    #pragma unroll
    for (int kk = 0; kk < 4; ++kk) {
        short8v a = *(short8v*)&tile[(rbase + r) * 68 + kk * 16 + g4];
        #pragma unroll
        for (int cb = 0; cb < 8; ++cb) {
            short8v wv = *(const short8v*)&WtA[(size_t)(cb * 16 + r) * 64 + kk * 16 + g4];
            acc1[cb] = __builtin_amdgcn_mfma_f32_16x16x32_bf16(wv, a, acc1[cb], 0, 0, 0);
        }
    }
    #pragma unroll
    for (int cb = 0; cb < 8; ++cb) {
        int c0 = cb * 16 + g4;
        float4 bi = *(const float4*)&bA[c0];
        float h0 = fmaxf(acc1[cb][0] + bi.x, 0.f);
        float h1 = fmaxf(acc1[cb][1] + bi.y, 0.f);
        float h2 = fmaxf(acc1[cb][2] + bi.z, 0.f);
        float h3 = fmaxf(acc1[cb][3] + bi.w, 0.f);
        uint2 pk;
        pk.x = f2bf(h0) | (f2bf(h1) << 16);
        pk.y = f2bf(h2) | (f2bf(h3) << 16);
        *(uint2*)&tile[(rbase + r) * 68 + (c0 >> 1)] = pk;
    }
    f32x4 acc2[8];
    #pragma unroll
    for (int cb = 0; cb < 8; ++cb) acc2[cb] = (f32x4){0.f, 0.f, 0.f, 0.f};
    #pragma unroll
    for (int kk = 0; kk < 4; ++kk) {
        short8v a = *(short8v*)&tile[(rbase + r) * 68 + kk * 16 + g4];
        #pragma unroll
        for (int cb = 0; cb < 8; ++cb) {
            short8v wv = *(const short8v*)&WtB[(size_t)(cb * 16 + r) * 64 + kk * 16 + g4];
            acc2[cb] = __builtin_amdgcn_mfma_f32_16x16x32_bf16(wv, a, acc2[cb], 0, 0, 0);
        }
    }
    int node = node0 + rbase + r;
    if (node < NN) {
        #pragma unroll
        for (int cb = 0; cb < 8; ++cb) {
            int c0 = cb * 16 + g4;
            float4 bi = *(const float4*)&bB[c0];
            float h0 = acc2[cb][0] + bi.x;
            float h1 = acc2[cb][1] + bi.y;
            float h2 = acc2[cb][2] + bi.z;
            float h3 = acc2[cb][3] + bi.w;
            uint2 pk;
            pk.x = f2bf(h0) | (f2bf(h1) << 16);
            pk.y = f2bf(h2) | (f2bf(h3) << 16);
            *(uint2*)&Pout[(size_t)node * 64 + (c0 >> 1)] = pk;
        }
    }
}

// ---------------- BN stats stage 1: per-block partials (no atomics) ----------------
__global__ __launch_bounds__(256) void bn_part_kernel(const unsigned int* __restrict__ P,
                                                      float* __restrict__ partial) {
    __shared__ float red[4][256];
    int t = threadIdx.x, l = t & 63, w = t >> 6;
    float s0 = 0.f, s1 = 0.f, q0 = 0.f, q1 = 0.f;
    for (int n = blockIdx.x * 4 + w; n < NN; n += BNBLK * 4) {
        unsigned int u = P[(size_t)n * 64 + l];
        float a = bf2f(u & 0xFFFFu), b = bf2f(u >> 16);
        s0 += a; q0 += a * a; s1 += b; q1 += b * b;
    }
    red[0][t] = s0; red[1][t] = s1; red[2][t] = q0; red[3][t] = q1;
    __syncthreads();
    if (t < 64) {
        float t0 = red[0][t] + red[0][t + 64] + red[0][t + 128] + red[0][t + 192];
        float t1 = red[1][t] + red[1][t + 64] + red[1][t + 128] + red[1][t + 192];
        float t2 = red[2][t] + red[2][t + 64] + red[2][t + 128] + red[2][t + 192];
        float t3 = red[3][t] + red[3][t + 64] + red[3][t + 128] + red[3][t + 192];
        float* pb = &partial[blockIdx.x * 256];
        pb[2 * t] = t0;
        pb[2 * t + 1] = t1;
        pb[128 + 2 * t] = t2;
        pb[128 + 2 * t + 1] = t3;
    }
}

// ---------------- BN stats stage 2: reduce partials ----------------
__global__ void bn_reduce_kernel(const float* __restrict__ partial, float* __restrict__ stats) {
    int t = threadIdx.x;   // 256
    float s = 0.f;
    for (int b = 0; b < BNBLK; ++b) s += partial[b * 256 + t];
    stats[t] = s;
}

// ---------------- BN + ReLU + repack ----------------
__global__ void bn_relu_pack_kernel(const unsigned int* __restrict__ Pin,
        const float* __restrict__ stats, const float* __restrict__ gamma,
        const float* __restrict__ beta, unsigned int* __restrict__ Pout) {
    int tid = blockIdx.x * 256 + threadIdx.x;   // NN*64 exact
    int l = tid & 63;
    int c0 = 2 * l;
    const float inv = 1.0f / NN;
    unsigned int u = Pin[tid];
    float u0 = bf2f(u & 0xFFFFu), u1 = bf2f(u >> 16);
    float m0 = stats[c0] * inv;
    float v0 = stats[128 + c0] * inv - m0 * m0;
    float m1 = stats[c0 + 1] * inv;
    float v1 = stats[128 + c0 + 1] * inv - m1 * m1;
    float o0 = fmaxf((u0 - m0) * rsqrtf(v0 + BN_EPS) * gamma[c0] + beta[c0], 0.f);
    float o1 = fmaxf((u1 - m1) * rsqrtf(v1 + BN_EPS) * gamma[c0 + 1] + beta[c0 + 1], 0.f);
    Pout[tid] = f2bf(o0) | (f2bf(o1) << 16);
}

// ---------------- pooling over packed rows ----------------
__global__ void pool_kernel(const unsigned int* __restrict__ hb,
                            const int* __restrict__ batch, float* __restrict__ pooled) {
    int g = blockIdx.x;
    int l = threadIdx.x;   // 64
    int a = 0, b = NN;
    while (a < b) { int m = (a + b) >> 1; if (batch[m] < g) a = m + 1; else b = m; }
    int start = a;
    b = NN;
    while (a < b) { int m = (a + b) >> 1; if (batch[m] < g + 1) a = m + 1; else b = m; }
    int end = a;
    float s0 = 0.f, s1 = 0.f;
    for (int i = start; i < end; ++i) {
        unsigned int u = hb[(size_t)i * 64 + l];
        s0 += bf2f(u & 0xFFFFu);
        s1 += bf2f(u >> 16);
    }
    ((float2*)pooled)[g * 64 + l] = make_float2(s0, s1);
}

// ---------------- head: logits + log_softmax ----------------
__global__ void head_kernel(const float* __restrict__ pooled, const float* __restrict__ Wlin,
                            const float* __restrict__ blin, float* __restrict__ out) {
    int g = blockIdx.x;
    int lane = threadIdx.x;  // 64
    float2 p = ((const float2*)pooled)[g * 64 + lane];
    float l[10];
    #pragma unroll
    for (int o = 0; o < 10; ++o) {
        float partial = p.x * Wlin[(2 * lane) * 10 + o] + p.y * Wlin[(2 * lane + 1) * 10 + o];
        #pragma unroll
        for (int m = 1; m < 64; m <<= 1) partial += __shfl_xor(partial, m, 64);
        l[o] = partial + blin[o];
    }
    float mx = l[0];
    #pragma unroll
    for (int o = 1; o < 10; ++o) mx = fmaxf(mx, l[o]);
    float se = 0.f;
    #pragma unroll
    for (int o = 0; o < 10; ++o) se += expf(l[o] - mx);
    float lse = mx + logf(se);
    if (lane == 0) {
        #pragma unroll
        for (int o = 0; o < 10; ++o) out[g * 10 + o] = l[o] - lse;
    }
}

extern "C" void kernel_launch(void* const* d_in, const int* in_sizes, int n_in,
                              void* d_out, int out_size, void* d_ws, size_t ws_size,
                              hipStream_t stream) {
    const float* x    = (const float*)d_in[0];
    const int*   edge = (const int*)d_in[1];   // [2][NE]
    const int*   batch= (const int*)d_in[2];
    const float* W1a  = (const float*)d_in[3];
    const float* b1a  = (const float*)d_in[4];
    const float* W1b  = (const float*)d_in[5];
    const float* b1b  = (const float*)d_in[6];
    const float* g1   = (const float*)d_in[7];
    const float* be1  = (const float*)d_in[8];
    const float* W2a  = (const float*)d_in[9];
    const float* b2a  = (const float*)d_in[10];
    const float* W2b  = (const float*)d_in[11];
    const float* b2b  = (const float*)d_in[12];
    const float* g2   = (const float*)d_in[13];
    const float* be2  = (const float*)d_in[14];
    const float* Wlin = (const float*)d_in[15];
    const float* blin = (const float*)d_in[16];
    float* out = (float*)d_out;

    char* ws = (char*)d_ws;
    size_t off = 0;
    auto alloc = [&](size_t bytes) -> void* {
        void* p = ws + off; off += (bytes + 255) & ~(size_t)255; return p;
    };
    unsigned int* Pa   = (unsigned int*)alloc((size_t)NN * 64 * 4);
    unsigned int* Pb   = (unsigned int*)alloc((size_t)NN * 64 * 4);
    unsigned int* ebin = (unsigned int*)alloc((size_t)NE * 4);
    int*   csrc   = (int*)alloc((size_t)NE * 4);
    int*   noffs  = (int*)alloc((NN + 1) * 4);
    int*   bcnt   = (int*)alloc(NBKT * 4);
    int*   bbase  = (int*)alloc(NBKT * 4);
    int*   bcur   = (int*)alloc(NBKT * 4);
    float* stats1 = (float*)alloc(256 * 4);
    float* stats2 = (float*)alloc(256 * 4);
    float* partial= (float*)alloc((size_t)BNBLK * 256 * 4);
    float* pooled = (float*)alloc(NG * 128 * 4);
    unsigned int* Wt = (unsigned int*)alloc(4 * 8192 * 4);
    unsigned int* Wt1a = Wt;
    unsigned int* Wt1b = Wt + 8192;
    unsigned int* Wt2a = Wt + 16384;
    unsigned int* Wt2b = Wt + 24576;

    const int* srcI = edge;
    const int* dstI = edge + NE;

    hipMemsetAsync(bcnt, 0, NBKT * 4, stream);

    bucket_count_kernel<<<NBINBLK, 256, 0, stream>>>(dstI, bcnt);
    bucket_scan_kernel<<<1, 1024, 0, stream>>>(bcnt, bbase, bcur);
    bin_kernel<<<NBINBLK, 256, 0, stream>>>(srcI, dstI, bcur, ebin);
    sort_kernel<<<NBKT, 256, 0, stream>>>(ebin, bbase, bcnt, noffs, csrc);
    wprep_kernel<<<128, 256, 0, stream>>>(W1a, W1b, W2a, W2b, Wt);
    pack_x_kernel<<<25000, 256, 0, stream>>>(x, Pa);

    // ---- layer 1 ----
    aggregate_gather_kernel<<<25000, 256, 0, stream>>>(Pa, noffs, csrc, Pb);
    mlp_kernel<<<1563, 256, 0, stream>>>(Pb, Wt1a, b1a, Wt1b, b1b, Pa);
    bn_part_kernel<<<BNBLK, 256, 0, stream>>>(Pa, partial);
    bn_reduce_kernel<<<1, 256, 0, stream>>>(partial, stats1);
    bn_relu_pack_kernel<<<25000, 256, 0, stream>>>(Pa, stats1, g1, be1, Pb);
    // ---- layer 2 ----
    aggregate_gather_kernel<<<25000, 256, 0, stream>>>(Pb, noffs, csrc, Pa);
    mlp_kernel<<<1563, 256, 0, stream>>>(Pa, Wt2a, b2a, Wt2b, b2b, Pb);
    bn_part_kernel<<<BNBLK, 256, 0, stream>>>(Pb, partial);
    bn_reduce_kernel<<<1, 256, 0, stream>>>(partial, stats2);
    bn_relu_pack_kernel<<<25000, 256, 0, stream>>>(Pb, stats2, g2, be2, Pa);

    pool_kernel<<<NG, 64, 0, stream>>>(Pa, batch, pooled);
    head_kernel<<<NG, 64, 0, stream>>>(pooled, Wlin, blin, out);
}